// Round 2
// 214.967 us; speedup vs baseline: 1.1628x; 1.1628x over previous
//
#include <hip/hip_runtime.h>

// Problem constants (match reference)
constexpr int N = 4096;   // nodes
constexpr int E = 4096;   // hyperedges
constexpr int F = 128;
constexpr int MAXL = 128; // list capacity per node/edge (deg ~ Binomial(4096,1/128), mean 32)
constexpr int DIAG_LD = 4097; // stride of diagonal in [4096][4096]

__device__ __forceinline__ ushort f2bf_rne(float x) {
    union { float f; unsigned u; } v; v.f = x;
    return (ushort)((v.u + 0x7FFFu + ((v.u >> 16) & 1u)) >> 16);
}

// ---------------------------------------------------------------------------
// theta_bf[n][f] = bf16( (X@W)[n][f] )  — [4096][128] bf16, node-major
// 256 blocks x 256 threads; 16 X-rows per block; thread = (half, f)
// ---------------------------------------------------------------------------
__global__ __launch_bounds__(256) void k_theta(const float* __restrict__ X,
                                               const float* __restrict__ W,
                                               ushort* __restrict__ theta_bf) {
    __shared__ float Xs[16][F];   // 8 KB
    const int t = threadIdx.x;
    const int r0 = blockIdx.x * 16;
    #pragma unroll
    for (int i = 0; i < 2; ++i) {
        const int idx = i * 256 + t;            // 0..511 float4s of the 16x128 tile
        const int rr = idx >> 5, cc = (idx & 31) * 4;
        *(float4*)&Xs[rr][cc] = *(const float4*)&X[(size_t)(r0 + rr) * F + cc];
    }
    __syncthreads();
    const int f = t & 127, half = t >> 7;       // half selects rows 0-7 / 8-15
    float acc[8];
    #pragma unroll
    for (int i = 0; i < 8; ++i) acc[i] = 0.f;
    #pragma unroll 4
    for (int k = 0; k < F; ++k) {
        const float w = W[k * F + f];           // coalesced, L1/L2-broadcast
        #pragma unroll
        for (int i = 0; i < 8; ++i) acc[i] += Xs[half * 8 + i][k] * w;
    }
    #pragma unroll
    for (int i = 0; i < 8; ++i)
        theta_bf[(size_t)(r0 + half * 8 + i) * F + f] = f2bf_rne(acc[i]);
}

// ---------------------------------------------------------------------------
// One pass over binary H: build both adjacency lists.
//   row_list[n][*] = edges e with H[n][e] != 0   (for SpMM2)
//   col_list[e][*] = nodes n with H[n][e] != 0   (for SpMM1)
// 1024 blocks x 256 threads; wave w scans row r = bid*4 + w (16 KB, coalesced).
// col_cnt must be zeroed before launch. List order is irrelevant (sums).
// ---------------------------------------------------------------------------
__global__ __launch_bounds__(256) void k_build(const float* __restrict__ H,
                                               int* __restrict__ row_cnt,
                                               ushort* __restrict__ row_list,
                                               int* __restrict__ col_cnt,
                                               ushort* __restrict__ col_list) {
    __shared__ int lcnt[4];
    const int t = threadIdx.x, wave = t >> 6, lane = t & 63;
    if (t < 4) lcnt[t] = 0;
    __syncthreads();
    const int r = blockIdx.x * 4 + wave;
    const float* Hr = H + (size_t)r * E;
    for (int j = 0; j < 4; ++j) {
        uint4 v[4];
        #pragma unroll
        for (int q = 0; q < 4; ++q)   // 4 loads in flight, 1 KB/wave each
            v[q] = *(const uint4*)&Hr[((j * 4 + q) * 64 + lane) * 4];
        #pragma unroll
        for (int q = 0; q < 4; ++q) {
            if (v[q].x | v[q].y | v[q].z | v[q].w) {   // ~3% of quads nonzero
                const int c0 = ((j * 4 + q) * 64 + lane) * 4;
                const uint vv[4] = {v[q].x, v[q].y, v[q].z, v[q].w};
                #pragma unroll
                for (int c = 0; c < 4; ++c) {
                    if (vv[c]) {
                        const int e = c0 + c;
                        const int p = atomicAdd(&lcnt[wave], 1);
                        if (p < MAXL) row_list[(size_t)r * MAXL + p] = (ushort)e;
                        const int g = atomicAdd(&col_cnt[e], 1);
                        if (g < MAXL) col_list[(size_t)e * MAXL + g] = (ushort)r;
                    }
                }
            }
        }
    }
    __syncthreads();
    if (lane == 0) row_cnt[r] = lcnt[wave] < MAXL ? lcnt[wave] : MAXL;
}

// ---------------------------------------------------------------------------
// Vout[r][:] = (1/Ddiag[r]) * sum_{i < cnt[r]} Vin[list[r][i]][:]
// One wave per output row; lane owns 2 columns (f = 2*lane, 2*lane+1).
// Vin is bf16 [4096][128] (L2-resident); gathers are 256 B coalesced rows.
// ---------------------------------------------------------------------------
template <bool OUT_BF16>
__global__ __launch_bounds__(256) void k_spmm(const int* __restrict__ cnt,
                                              const ushort* __restrict__ list,
                                              const ushort* __restrict__ Vin,
                                              const float* __restrict__ Dmat,
                                              void* __restrict__ Vout) {
    __shared__ ushort sIdx[4][MAXL];    // 1 KB
    const int t = threadIdx.x, wave = t >> 6, lane = t & 63;
    const int r = blockIdx.x * 4 + wave;
    *(ushort2*)&sIdx[wave][lane * 2] =
        *(const ushort2*)&list[(size_t)r * MAXL + lane * 2];
    int c = cnt[r]; c = c < MAXL ? c : MAXL;
    const float dscale = 1.0f / Dmat[(size_t)r * DIAG_LD];  // overlap with gathers
    __syncthreads();
    const char* vb = (const char*)Vin;
    float a0 = 0.f, a1 = 0.f;
    int i = 0;
    for (; i + 8 <= c; i += 8) {        // 8 gathers in flight
        uint v[8];
        #pragma unroll
        for (int j = 0; j < 8; ++j)
            v[j] = *(const uint*)(vb + ((int)sIdx[wave][i + j] * 256 + lane * 4));
        #pragma unroll
        for (int j = 0; j < 8; ++j) {
            a0 += __uint_as_float((v[j] & 0xffffu) << 16);
            a1 += __uint_as_float((v[j] >> 16) << 16);
        }
    }
    for (; i < c; ++i) {
        const uint v = *(const uint*)(vb + ((int)sIdx[wave][i] * 256 + lane * 4));
        a0 += __uint_as_float((v & 0xffffu) << 16);
        a1 += __uint_as_float((v >> 16) << 16);
    }
    a0 *= dscale; a1 *= dscale;
    if (OUT_BF16) {
        ushort2 o; o.x = f2bf_rne(a0); o.y = f2bf_rne(a1);
        *(ushort2*)((ushort*)Vout + (size_t)r * F + lane * 2) = o;
    } else {
        float2 o; o.x = a0; o.y = a1;
        *(float2*)((float*)Vout + (size_t)r * F + lane * 2) = o;
    }
}

// ---------------------------------------------------------------------------
extern "C" void kernel_launch(void* const* d_in, const int* in_sizes, int n_in,
                              void* d_out, int out_size, void* d_ws, size_t ws_size,
                              hipStream_t stream) {
    const float* X  = (const float*)d_in[0];   // [N,128]
    const float* H  = (const float*)d_in[1];   // [N,E] fp32 (binary)
    const float* Dv = (const float*)d_in[2];   // [N,N]
    const float* De = (const float*)d_in[3];   // [E,E]
    const float* W  = (const float*)d_in[4];   // [128,128]
    float* out = (float*)d_out;                // [N,128]
    char* ws = (char*)d_ws;

    // workspace layout (4 MB + 32 KB)
    ushort* theta    = (ushort*)ws;                                  // 1 MB [n][f] bf16
    ushort* M        = (ushort*)(ws + (size_t)1 * 1024 * 1024);      // 1 MB [e][f] bf16
    ushort* row_list = (ushort*)(ws + (size_t)2 * 1024 * 1024);      // 1 MB [n][MAXL]
    ushort* col_list = (ushort*)(ws + (size_t)3 * 1024 * 1024);      // 1 MB [e][MAXL]
    int*    row_cnt  = (int*)   (ws + (size_t)4 * 1024 * 1024);      // 16 KB
    int*    col_cnt  = row_cnt + N;                                  // 16 KB

    hipMemsetAsync(col_cnt, 0, (size_t)E * sizeof(int), stream);

    k_theta<<<dim3(N / 16), dim3(256), 0, stream>>>(X, W, theta);
    k_build<<<dim3(N / 4), dim3(256), 0, stream>>>(H, row_cnt, row_list,
                                                   col_cnt, col_list);
    // SpMM1: M[e][f] = (1/de[e]) * sum_{n in edge e} theta[n][f]
    k_spmm<true ><<<dim3(E / 4), dim3(256), 0, stream>>>(col_cnt, col_list,
                                                         theta, De, M);
    // SpMM2: out[n][f] = (1/dv[n]) * sum_{e at node n} M[e][f]
    k_spmm<false><<<dim3(N / 4), dim3(256), 0, stream>>>(row_cnt, row_list,
                                                         M, Dv, out);
}

// Round 3
// 207.129 us; speedup vs baseline: 1.2068x; 1.0378x over previous
//
#include <hip/hip_runtime.h>

// Problem constants (match reference)
constexpr int N = 4096;   // nodes
constexpr int E = 4096;   // hyperedges
constexpr int F = 128;
constexpr int MAXL = 128; // list capacity per node/edge (deg ~ Binomial(4096,1/128), mean 32)
constexpr int DIAG_LD = 4097; // stride of diagonal in [4096][4096]

__device__ __forceinline__ ushort f2bf_rne(float x) {
    union { float f; unsigned u; } v; v.f = x;
    return (ushort)((v.u + 0x7FFFu + ((v.u >> 16) & 1u)) >> 16);
}

// ---------------------------------------------------------------------------
// theta_bf[n][f] = bf16( (X@W)[n][f] )  — [4096][128] bf16, node-major
// ---------------------------------------------------------------------------
__global__ __launch_bounds__(256) void k_theta(const float* __restrict__ X,
                                               const float* __restrict__ W,
                                               ushort* __restrict__ theta_bf) {
    __shared__ float Xs[16][F];   // 8 KB
    const int t = threadIdx.x;
    const int r0 = blockIdx.x * 16;
    #pragma unroll
    for (int i = 0; i < 2; ++i) {
        const int idx = i * 256 + t;            // 0..511 float4s of the 16x128 tile
        const int rr = idx >> 5, cc = (idx & 31) * 4;
        *(float4*)&Xs[rr][cc] = *(const float4*)&X[(size_t)(r0 + rr) * F + cc];
    }
    __syncthreads();
    const int f = t & 127, half = t >> 7;       // half selects rows 0-7 / 8-15
    float acc[8];
    #pragma unroll
    for (int i = 0; i < 8; ++i) acc[i] = 0.f;
    #pragma unroll 4
    for (int k = 0; k < F; ++k) {
        const float w = W[k * F + f];           // coalesced, L1/L2-broadcast
        #pragma unroll
        for (int i = 0; i < 8; ++i) acc[i] += Xs[half * 8 + i][k] * w;
    }
    #pragma unroll
    for (int i = 0; i < 8; ++i)
        theta_bf[(size_t)(r0 + half * 8 + i) * F + f] = f2bf_rne(acc[i]);
}

// ---------------------------------------------------------------------------
// Pass 1 (row-major sweep of H, NO global atomics):
//   - row_list[n][*] / row_cnt[n] via per-wave LDS list (coalesced write-out)
//   - BM bitmask of H: word W = chunk i = W>>2, comp c = W&3;
//     bit l of word W  <->  column  (W>>2)*256 + 4*l + (W&3)
// 1024 blocks x 256 threads; wave w owns row r = 4*bid + w (16 KB coalesced).
// ---------------------------------------------------------------------------
__global__ __launch_bounds__(256) void k_pass1(const float* __restrict__ H,
                                               unsigned long long* __restrict__ BM,
                                               int* __restrict__ row_cnt,
                                               ushort* __restrict__ row_list) {
    __shared__ ushort sL[4][MAXL];   // 1 KB row lists
    __shared__ int lcnt[4];
    const int t = threadIdx.x, wave = t >> 6, lane = t & 63;
    if (lane == 0) lcnt[wave] = 0;   // same-wave producer/consumer: no barrier needed
    const int r = blockIdx.x * 4 + wave;
    const float* Hr = H + (size_t)r * E;
    #pragma unroll
    for (int half = 0; half < 2; ++half) {
        uint4 v[8];
        #pragma unroll
        for (int q = 0; q < 8; ++q)   // 8 KB/wave in flight, fully coalesced
            v[q] = *(const uint4*)&Hr[((half * 8 + q) * 64 + lane) * 4];
        unsigned long long wreg = 0;
        #pragma unroll
        for (int q = 0; q < 8; ++q) {
            const int i = half * 8 + q;                  // chunk 0..15
            const uint vv[4] = {v[q].x, v[q].y, v[q].z, v[q].w};
            #pragma unroll
            for (int c = 0; c < 4; ++c) {
                const unsigned long long m = __ballot(vv[c] != 0u);
                const int widx = q * 4 + c;              // word within half: 0..31
                if (lane == widx) wreg = m;              // stage for coalesced store
                if (vv[c]) {                             // ~0.8% of lanes
                    const int p = atomicAdd(&lcnt[wave], 1);   // LDS atomic
                    if (p < MAXL) sL[wave][p] = (ushort)(i * 256 + 4 * lane + c);
                }
            }
        }
        if (lane < 32)                                   // 256 B coalesced store
            BM[(size_t)r * 64 + half * 32 + lane] = wreg;
    }
    const int cnt = lcnt[wave] < MAXL ? lcnt[wave] : MAXL;
    // coalesced 256 B list write-out (entries beyond cnt are unused garbage)
    ((uint*)&row_list[(size_t)r * MAXL])[lane] = ((const uint*)sL[wave])[lane];
    if (lane == 0) row_cnt[r] = cnt;
}

// ---------------------------------------------------------------------------
// Pass 2 (column lists from the 2 MB bitmask, LDS atomics only):
// 64 blocks x 512 threads; block owns word-column wc (64 edges).
// Lane reads 8 words (rows wave*512 + j*64 + lane), extracts set bits,
// appends row index into per-edge LDS list; coalesced 16 KB write-out.
// ---------------------------------------------------------------------------
__global__ __launch_bounds__(512) void k_pass2(
        const unsigned long long* __restrict__ BM,
        int* __restrict__ col_cnt,
        ushort* __restrict__ col_list) {
    __shared__ ushort sL[64][MAXL];   // 16 KB
    __shared__ int cnt[64];
    const int t = threadIdx.x, wave = t >> 6, lane = t & 63;
    const int wc = blockIdx.x;        // word-column 0..63
    if (t < 64) cnt[t] = 0;
    __syncthreads();
    unsigned long long w8[8];
    #pragma unroll
    for (int j = 0; j < 8; ++j)       // 8 x 8 B loads in flight (stride 512 B)
        w8[j] = BM[(size_t)(wave * 512 + j * 64 + lane) * 64 + wc];
    #pragma unroll
    for (int j = 0; j < 8; ++j) {
        unsigned long long m = w8[j];
        const ushort row = (ushort)(wave * 512 + j * 64 + lane);
        while (m) {                   // avg 0.5 set bits per word
            const int b = __builtin_ctzll(m); m &= m - 1;
            const int p = atomicAdd(&cnt[b], 1);          // LDS atomic
            if (p < MAXL) sL[b][p] = row;
        }
    }
    __syncthreads();
    // write-out: 64 edges x 256 B; 8 threads per edge
    const int el = t >> 3, ch = t & 7;
    const int e = (wc >> 2) * 256 + 4 * el + (wc & 3);    // bit->column mapping
    const uint4* src = (const uint4*)sL[el];
    uint4* dst = (uint4*)&col_list[(size_t)e * MAXL];
    dst[ch * 2 + 0] = src[ch * 2 + 0];
    dst[ch * 2 + 1] = src[ch * 2 + 1];
    if (ch == 0) col_cnt[e] = cnt[el] < MAXL ? cnt[el] : MAXL;
}

// ---------------------------------------------------------------------------
// Vout[r][:] = (1/Ddiag[r]) * sum_{i < cnt[r]} Vin[list[r][i]][:]
// One wave per output row; lane owns 2 columns (f = 2*lane, 2*lane+1).
// ---------------------------------------------------------------------------
template <bool OUT_BF16>
__global__ __launch_bounds__(256) void k_spmm(const int* __restrict__ cnt,
                                              const ushort* __restrict__ list,
                                              const ushort* __restrict__ Vin,
                                              const float* __restrict__ Dmat,
                                              void* __restrict__ Vout) {
    __shared__ ushort sIdx[4][MAXL];    // 1 KB
    const int t = threadIdx.x, wave = t >> 6, lane = t & 63;
    const int r = blockIdx.x * 4 + wave;
    *(ushort2*)&sIdx[wave][lane * 2] =
        *(const ushort2*)&list[(size_t)r * MAXL + lane * 2];
    int c = cnt[r]; c = c < MAXL ? c : MAXL;
    const float dscale = 1.0f / Dmat[(size_t)r * DIAG_LD];  // overlaps gathers
    __syncthreads();
    const char* vb = (const char*)Vin;
    float a0 = 0.f, a1 = 0.f;
    int i = 0;
    for (; i + 8 <= c; i += 8) {        // 8 gathers in flight
        uint v[8];
        #pragma unroll
        for (int j = 0; j < 8; ++j)
            v[j] = *(const uint*)(vb + ((int)sIdx[wave][i + j] * 256 + lane * 4));
        #pragma unroll
        for (int j = 0; j < 8; ++j) {
            a0 += __uint_as_float((v[j] & 0xffffu) << 16);
            a1 += __uint_as_float((v[j] >> 16) << 16);
        }
    }
    for (; i < c; ++i) {
        const uint v = *(const uint*)(vb + ((int)sIdx[wave][i] * 256 + lane * 4));
        a0 += __uint_as_float((v & 0xffffu) << 16);
        a1 += __uint_as_float((v >> 16) << 16);
    }
    a0 *= dscale; a1 *= dscale;
    if (OUT_BF16) {
        ushort2 o; o.x = f2bf_rne(a0); o.y = f2bf_rne(a1);
        *(ushort2*)((ushort*)Vout + (size_t)r * F + lane * 2) = o;
    } else {
        float2 o; o.x = a0; o.y = a1;
        *(float2*)((float*)Vout + (size_t)r * F + lane * 2) = o;
    }
}

// ---------------------------------------------------------------------------
extern "C" void kernel_launch(void* const* d_in, const int* in_sizes, int n_in,
                              void* d_out, int out_size, void* d_ws, size_t ws_size,
                              hipStream_t stream) {
    const float* X  = (const float*)d_in[0];   // [N,128]
    const float* H  = (const float*)d_in[1];   // [N,E] fp32 (binary)
    const float* Dv = (const float*)d_in[2];   // [N,N]
    const float* De = (const float*)d_in[3];   // [E,E]
    const float* W  = (const float*)d_in[4];   // [128,128]
    float* out = (float*)d_out;                // [N,128]
    char* ws = (char*)d_ws;

    // workspace layout (~5.03 MB)
    ushort* theta    = (ushort*)ws;                                  // 1 MB [n][f] bf16
    unsigned long long* BM =
        (unsigned long long*)(ws + (size_t)1 * 1024 * 1024);         // 2 MB bitmask
    ushort* M        = (ushort*)(ws + (size_t)1 * 1024 * 1024);      // 1 MB, ALIASES BM
                                                                     // (BM dead after pass2)
    ushort* row_list = (ushort*)(ws + (size_t)3 * 1024 * 1024);      // 1 MB [n][MAXL]
    ushort* col_list = (ushort*)(ws + (size_t)4 * 1024 * 1024);      // 1 MB [e][MAXL]
    int*    row_cnt  = (int*)   (ws + (size_t)5 * 1024 * 1024);      // 16 KB
    int*    col_cnt  = row_cnt + N;                                  // 16 KB

    k_theta<<<dim3(N / 16), dim3(256), 0, stream>>>(X, W, theta);
    k_pass1<<<dim3(N / 4), dim3(256), 0, stream>>>(H, BM, row_cnt, row_list);
    k_pass2<<<dim3(64), dim3(512), 0, stream>>>(BM, col_cnt, col_list);
    // SpMM1: M[e][f] = (1/de[e]) * sum_{n in edge e} theta[n][f]  (overwrites BM)
    k_spmm<true ><<<dim3(E / 4), dim3(256), 0, stream>>>(col_cnt, col_list,
                                                         theta, De, M);
    // SpMM2: out[n][f] = (1/dv[n]) * sum_{e at node n} M[e][f]
    k_spmm<false><<<dim3(N / 4), dim3(256), 0, stream>>>(row_cnt, row_list,
                                                         M, Dv, out);
}

// Round 4
// 199.369 us; speedup vs baseline: 1.2538x; 1.0389x over previous
//
#include <hip/hip_runtime.h>

// Problem constants (match reference)
constexpr int N = 4096;   // nodes
constexpr int E = 4096;   // hyperedges
constexpr int F = 128;
constexpr int MAXL = 128; // list capacity per node/edge (deg ~ Binomial(4096,1/128), mean 32)
constexpr int DIAG_LD = 4097; // stride of diagonal in [4096][4096]

__device__ __forceinline__ ushort f2bf_rne(float x) {
    union { float f; unsigned u; } v; v.f = x;
    return (ushort)((v.u + 0x7FFFu + ((v.u >> 16) & 1u)) >> 16);
}

// ---------------------------------------------------------------------------
// Fused launch 1 (block-specialized, independent halves):
//   blocks 0..4095   : pass1 — ONE H row per block (max MLP: 4x uint4/lane
//                      issued up-front; 64 waves/CU oversubscribed).
//                      Emits bitmask word W = wave*16 + s*4 + c, whose bit l
//                      corresponds to column (W>>2)*256 + 4*l + (W&3)
//                      (identical convention to k_pass2's decode).
//   blocks 4096..4351: theta_bf[n][f] = bf16((X@W)[n][f]), 16 rows per block.
// ---------------------------------------------------------------------------
__global__ __launch_bounds__(256) void k_fused1(
        const float* __restrict__ H,
        const float* __restrict__ X,
        const float* __restrict__ Wm,
        unsigned long long* __restrict__ BM,
        int* __restrict__ row_cnt,
        ushort* __restrict__ row_list,
        ushort* __restrict__ theta_bf) {
    __shared__ float smem[16 * F];   // 8 KB, dual-purpose
    const int t = threadIdx.x;

    if (blockIdx.x < (unsigned)N) {
        // ----- pass1: row r of H -----
        ushort* sL   = (ushort*)smem;          // 256 B list
        int*    lcnt = (int*)(smem + 128);     // 4 B counter (disjoint)
        const int wave = t >> 6, lane = t & 63;
        if (t == 0) *lcnt = 0;
        __syncthreads();
        const int r = blockIdx.x;
        const float* Hr = H + (size_t)r * E;
        uint4 v[4];
        #pragma unroll
        for (int s = 0; s < 4; ++s)            // 4 x 1 KB/wave in flight
            v[s] = *(const uint4*)&Hr[(wave * 256 + s * 64 + lane) * 4];
        unsigned long long wreg = 0;
        #pragma unroll
        for (int s = 0; s < 4; ++s) {
            const uint vv[4] = {v[s].x, v[s].y, v[s].z, v[s].w};
            #pragma unroll
            for (int c = 0; c < 4; ++c) {
                const unsigned long long m = __ballot(vv[c] != 0u);
                if (lane == s * 4 + c) wreg = m;     // stage for coalesced store
                if (vv[c]) {                         // ~0.8% of lanes
                    const int p = atomicAdd(lcnt, 1);             // LDS atomic
                    if (p < MAXL)
                        sL[p] = (ushort)(wave * 1024 + s * 256 + 4 * lane + c);
                }
            }
        }
        if (lane < 16)                               // 128 B coalesced per wave
            BM[(size_t)r * 64 + wave * 16 + lane] = wreg;
        __syncthreads();
        if (wave == 0) {                             // 256 B coalesced write-out
            ((uint*)&row_list[(size_t)r * MAXL])[lane] = ((const uint*)sL)[lane];
            if (lane == 0) row_cnt[r] = *lcnt < MAXL ? *lcnt : MAXL;
        }
    } else {
        // ----- theta: rows r0..r0+15 of X@W -----
        float (*Xs)[F] = (float(*)[F])smem;
        const int r0 = (blockIdx.x - N) * 16;
        #pragma unroll
        for (int i = 0; i < 2; ++i) {
            const int idx = i * 256 + t;             // float4s of the 16x128 tile
            const int rr = idx >> 5, cc = (idx & 31) * 4;
            *(float4*)&Xs[rr][cc] = *(const float4*)&X[(size_t)(r0 + rr) * F + cc];
        }
        __syncthreads();
        const int f = t & 127, half = t >> 7;
        float acc[8];
        #pragma unroll
        for (int i = 0; i < 8; ++i) acc[i] = 0.f;
        #pragma unroll 4
        for (int k = 0; k < F; ++k) {
            const float w = Wm[k * F + f];
            #pragma unroll
            for (int i = 0; i < 8; ++i) acc[i] += Xs[half * 8 + i][k] * w;
        }
        #pragma unroll
        for (int i = 0; i < 8; ++i)
            theta_bf[(size_t)(r0 + half * 8 + i) * F + f] = f2bf_rne(acc[i]);
    }
}

// ---------------------------------------------------------------------------
// Pass 2 (column lists from the 2 MB bitmask, LDS atomics only):
// 64 blocks x 512 threads; block owns word-column wc (64 edges).
// ---------------------------------------------------------------------------
__global__ __launch_bounds__(512) void k_pass2(
        const unsigned long long* __restrict__ BM,
        int* __restrict__ col_cnt,
        ushort* __restrict__ col_list) {
    __shared__ ushort sL[64][MAXL];   // 16 KB
    __shared__ int cnt[64];
    const int t = threadIdx.x, wave = t >> 6, lane = t & 63;
    const int wc = blockIdx.x;        // word-column 0..63
    if (t < 64) cnt[t] = 0;
    __syncthreads();
    unsigned long long w8[8];
    #pragma unroll
    for (int j = 0; j < 8; ++j)       // 8 x 8 B loads in flight
        w8[j] = BM[(size_t)(wave * 512 + j * 64 + lane) * 64 + wc];
    #pragma unroll
    for (int j = 0; j < 8; ++j) {
        unsigned long long m = w8[j];
        const ushort row = (ushort)(wave * 512 + j * 64 + lane);
        while (m) {                   // avg 0.5 set bits per word
            const int b = __builtin_ctzll(m); m &= m - 1;
            const int p = atomicAdd(&cnt[b], 1);          // LDS atomic
            if (p < MAXL) sL[b][p] = row;
        }
    }
    __syncthreads();
    // write-out: 64 edges x 256 B; 8 threads per edge
    const int el = t >> 3, ch = t & 7;
    const int e = (wc >> 2) * 256 + 4 * el + (wc & 3);    // bit->column mapping
    const uint4* src = (const uint4*)sL[el];
    uint4* dst = (uint4*)&col_list[(size_t)e * MAXL];
    dst[ch * 2 + 0] = src[ch * 2 + 0];
    dst[ch * 2 + 1] = src[ch * 2 + 1];
    if (ch == 0) col_cnt[e] = cnt[el] < MAXL ? cnt[el] : MAXL;
}

// ---------------------------------------------------------------------------
// Vout[r][:] = (1/Ddiag[r]) * sum_{i < cnt[r]} Vin[list[r][i]][:]
// One wave per output row; lane owns 2 columns; 16 gathers in flight.
// ---------------------------------------------------------------------------
template <bool OUT_BF16>
__global__ __launch_bounds__(256) void k_spmm(const int* __restrict__ cnt,
                                              const ushort* __restrict__ list,
                                              const ushort* __restrict__ Vin,
                                              const float* __restrict__ Dmat,
                                              void* __restrict__ Vout) {
    __shared__ ushort sIdx[4][MAXL];    // 1 KB
    const int t = threadIdx.x, wave = t >> 6, lane = t & 63;
    const int r = blockIdx.x * 4 + wave;
    *(ushort2*)&sIdx[wave][lane * 2] =
        *(const ushort2*)&list[(size_t)r * MAXL + lane * 2];
    int c = cnt[r]; c = c < MAXL ? c : MAXL;
    const float dscale = 1.0f / Dmat[(size_t)r * DIAG_LD];  // overlaps gathers
    __syncthreads();
    const char* vb = (const char*)Vin;
    float a0 = 0.f, a1 = 0.f;
    int i = 0;
    for (; i + 16 <= c; i += 16) {      // 16 gathers in flight
        uint v[16];
        #pragma unroll
        for (int j = 0; j < 16; ++j)
            v[j] = *(const uint*)(vb + ((int)sIdx[wave][i + j] * 256 + lane * 4));
        #pragma unroll
        for (int j = 0; j < 16; ++j) {
            a0 += __uint_as_float((v[j] & 0xffffu) << 16);
            a1 += __uint_as_float((v[j] >> 16) << 16);
        }
    }
    for (; i + 4 <= c; i += 4) {
        uint v[4];
        #pragma unroll
        for (int j = 0; j < 4; ++j)
            v[j] = *(const uint*)(vb + ((int)sIdx[wave][i + j] * 256 + lane * 4));
        #pragma unroll
        for (int j = 0; j < 4; ++j) {
            a0 += __uint_as_float((v[j] & 0xffffu) << 16);
            a1 += __uint_as_float((v[j] >> 16) << 16);
        }
    }
    for (; i < c; ++i) {
        const uint v = *(const uint*)(vb + ((int)sIdx[wave][i] * 256 + lane * 4));
        a0 += __uint_as_float((v & 0xffffu) << 16);
        a1 += __uint_as_float((v >> 16) << 16);
    }
    a0 *= dscale; a1 *= dscale;
    if (OUT_BF16) {
        ushort2 o; o.x = f2bf_rne(a0); o.y = f2bf_rne(a1);
        *(ushort2*)((ushort*)Vout + (size_t)r * F + lane * 2) = o;
    } else {
        float2 o; o.x = a0; o.y = a1;
        *(float2*)((float*)Vout + (size_t)r * F + lane * 2) = o;
    }
}

// ---------------------------------------------------------------------------
extern "C" void kernel_launch(void* const* d_in, const int* in_sizes, int n_in,
                              void* d_out, int out_size, void* d_ws, size_t ws_size,
                              hipStream_t stream) {
    const float* X  = (const float*)d_in[0];   // [N,128]
    const float* H  = (const float*)d_in[1];   // [N,E] fp32 (binary)
    const float* Dv = (const float*)d_in[2];   // [N,N]
    const float* De = (const float*)d_in[3];   // [E,E]
    const float* W  = (const float*)d_in[4];   // [128,128]
    float* out = (float*)d_out;                // [N,128]
    char* ws = (char*)d_ws;

    // workspace layout (~5.03 MB)
    ushort* theta    = (ushort*)ws;                                  // 1 MB [n][f] bf16
    unsigned long long* BM =
        (unsigned long long*)(ws + (size_t)1 * 1024 * 1024);         // 2 MB bitmask
    ushort* M        = (ushort*)(ws + (size_t)1 * 1024 * 1024);      // 1 MB, ALIASES BM
                                                                     // (BM dead after pass2)
    ushort* row_list = (ushort*)(ws + (size_t)3 * 1024 * 1024);      // 1 MB [n][MAXL]
    ushort* col_list = (ushort*)(ws + (size_t)4 * 1024 * 1024);      // 1 MB [e][MAXL]
    int*    row_cnt  = (int*)   (ws + (size_t)5 * 1024 * 1024);      // 16 KB
    int*    col_cnt  = row_cnt + N;                                  // 16 KB

    // L1: pass1 (4096 blocks) + theta (256 blocks), independent halves
    k_fused1<<<dim3(N + N / 16), dim3(256), 0, stream>>>(
        H, X, W, BM, row_cnt, row_list, theta);
    // L2: column lists from bitmask
    k_pass2<<<dim3(64), dim3(512), 0, stream>>>(BM, col_cnt, col_list);
    // L3: M[e][f] = (1/de[e]) * sum_{n in edge e} theta[n][f]  (overwrites BM)
    k_spmm<true ><<<dim3(E / 4), dim3(256), 0, stream>>>(col_cnt, col_list,
                                                         theta, De, M);
    // L4: out[n][f] = (1/dv[n]) * sum_{e at node n} M[e][f]
    k_spmm<false><<<dim3(N / 4), dim3(256), 0, stream>>>(row_cnt, row_list,
                                                         M, Dv, out);
}